// Round 7
// baseline (1253.432 us; speedup 1.0000x reference)
//
#include <hip/hip_runtime.h>
#include <hip/hip_bf16.h>
#include <cstdint>
#include <cstddef>

#define N_NODES 100000
#define N_EDGES 800000
#define IN_DIM 128
#define HID_DIM 256
#define OUT_DIM 128

// deg fixed-point scale: 2^21. Max per-node wsum before low-word carry is
// 2^11 edges/node; random graph max-degree ~30. Per-edge quant error 2^-21.
#define DEG_SCALE 2097152.0f
#define DEG_INV   (1.0f / 2097152.0f)

// R14: 2048 blocks = EXACT residency capacity (VGPR 44 <= 64 -> 8 blocks/CU
// x 256 CU; R6 measured 23.9% occupancy at 512 blocks = 512/2048, which
// quartered the gather phases' concurrency and tripled mega's time).
#define MEGA_BLOCKS 2048
#define MEGA_GT (MEGA_BLOCKS * 256)   // 524288 threads = full machine

typedef __attribute__((ext_vector_type(8))) short bf16x8;
typedef __attribute__((ext_vector_type(4))) float f32x4;

__device__ __forceinline__ unsigned short f32_to_bf16(float f) {
    __hip_bfloat16 b = __float2bfloat16(f);   // RNE
    return *reinterpret_cast<unsigned short*>(&b);
}
__device__ __forceinline__ float bf16_lo(uint32_t u) {
    uint32_t v = u << 16; return *reinterpret_cast<float*>(&v);
}
__device__ __forceinline__ float bf16_hi(uint32_t u) {
    uint32_t v = u & 0xffff0000u; return *reinterpret_cast<float*>(&v);
}

// ---------------------------------------------------------------------------
// Manual grid barrier — VALIDATED in R6 (passed, absmax == baseline).
// Device-scope atomics + __threadfence per G16; one counter per barrier
// instance (memset-zeroed each launch); relaxed agent-scope spin + s_sleep.
// Deadlock-safe iff all MEGA_BLOCKS are co-resident (guaranteed: 44 VGPR,
// 1KB LDS, launch_bounds(256,8) -> 8 blocks/CU x 256 CU = 2048).
// ---------------------------------------------------------------------------
__device__ __forceinline__ void grid_bar(unsigned int* b, unsigned int n) {
    __syncthreads();
    if (threadIdx.x == 0) {
        __threadfence();                               // release my stores
        atomicAdd(b, 1u);                              // device-scope arrive
        while (__hip_atomic_load(b, __ATOMIC_RELAXED,
                                 __HIP_MEMORY_SCOPE_AGENT) < n)
            __builtin_amdgcn_s_sleep(2);
        __threadfence();                               // acquire others' stores
    }
    __syncthreads();
}

// ---------------------------------------------------------------------------
// Shared aggregate body: 16 lanes/node, uint4 = 8 bf16 dims/lane.
// Weight in pairs[].y is pre-normalized (w*dis[src]*dis[dst]). Masked tail
// slots clamp to end-1 (just-touched line) with w=0.
// ---------------------------------------------------------------------------
__device__ __forceinline__ void acc_edge(float w, uint4 u, float* a) {
    a[0] += w * bf16_lo(u.x); a[1] += w * bf16_hi(u.x);
    a[2] += w * bf16_lo(u.y); a[3] += w * bf16_hi(u.y);
    a[4] += w * bf16_lo(u.z); a[5] += w * bf16_hi(u.z);
    a[6] += w * bf16_lo(u.w); a[7] += w * bf16_hi(u.w);
}

template <bool OUT_BF16>
__device__ __forceinline__ void agg_node(const uint4* __restrict__ feat,
                                         const int* __restrict__ rowp,
                                         const int2* __restrict__ pairs,
                                         void* __restrict__ out_v,
                                         const float* __restrict__ bias,
                                         int node, int lane) {
    int beg = rowp[node], end = rowp[node + 1];
    float a[8] = {};

    int j = beg;
    for (; j + 8 <= end; j += 8) {
        int2 p[8]; uint4 u[8];
        #pragma unroll
        for (int q = 0; q < 8; ++q) p[q] = pairs[j + q];
        #pragma unroll
        for (int q = 0; q < 8; ++q) u[q] = feat[(size_t)p[q].x * 16 + lane];
        #pragma unroll
        for (int q = 0; q < 8; ++q) acc_edge(__int_as_float(p[q].y), u[q], a);
    }
    int r = end - j;
    if (r > 4) {
        int2 p[8]; uint4 u[8];
        #pragma unroll
        for (int q = 0; q < 8; ++q) p[q] = pairs[(j + q < end) ? j + q : end - 1];
        #pragma unroll
        for (int q = 0; q < 8; ++q) u[q] = feat[(size_t)p[q].x * 16 + lane];
        #pragma unroll
        for (int q = 0; q < 8; ++q) {
            float w = (j + q < end) ? __int_as_float(p[q].y) : 0.f;
            acc_edge(w, u[q], a);
        }
    } else if (r > 0) {
        int2 p[4]; uint4 u[4];
        #pragma unroll
        for (int q = 0; q < 4; ++q) p[q] = pairs[(j + q < end) ? j + q : end - 1];
        #pragma unroll
        for (int q = 0; q < 4; ++q) u[q] = feat[(size_t)p[q].x * 16 + lane];
        #pragma unroll
        for (int q = 0; q < 4; ++q) {
            float w = (j + q < end) ? __int_as_float(p[q].y) : 0.f;
            acc_edge(w, u[q], a);
        }
    }

    if (bias) {
        float4 b0 = ((const float4*)bias)[lane * 2];
        float4 b1 = ((const float4*)bias)[lane * 2 + 1];
        a[0] += b0.x; a[1] += b0.y; a[2] += b0.z; a[3] += b0.w;
        a[4] += b1.x; a[5] += b1.y; a[6] += b1.z; a[7] += b1.w;
    }
    if (OUT_BF16) {
        uint4 o;
        o.x = (uint32_t)f32_to_bf16(a[0]) | ((uint32_t)f32_to_bf16(a[1]) << 16);
        o.y = (uint32_t)f32_to_bf16(a[2]) | ((uint32_t)f32_to_bf16(a[3]) << 16);
        o.z = (uint32_t)f32_to_bf16(a[4]) | ((uint32_t)f32_to_bf16(a[5]) << 16);
        o.w = (uint32_t)f32_to_bf16(a[6]) | ((uint32_t)f32_to_bf16(a[7]) << 16);
        ((uint4*)out_v)[(size_t)node * 16 + lane] = o;
    } else {
        ((float4*)out_v)[(size_t)node * 32 + lane * 2] =
            make_float4(a[0], a[1], a[2], a[3]);
        ((float4*)out_v)[(size_t)node * 32 + lane * 2 + 1] =
            make_float4(a[4], a[5], a[6], a[7]);
    }
}

// ---------------------------------------------------------------------------
// Mega-kernel = hist+prep -> scan1 -> scan23 -> place -> agg1 with manual
// device-scope barriers (mechanism validated R6). Collapses 5 launches -> 1.
// ---------------------------------------------------------------------------
__global__ __launch_bounds__(256, 8) void mega_kernel(
    const int* __restrict__ ei, const float* __restrict__ ew,
    unsigned long long* __restrict__ cnt64, int* __restrict__ rank,
    const float* __restrict__ x, uint32_t* __restrict__ xb,
    const float* __restrict__ W1, unsigned short* __restrict__ W1F,
    const float* __restrict__ W2, unsigned short* __restrict__ W2F,
    int* __restrict__ rowp, int* __restrict__ bsums, float* __restrict__ dis,
    int2* __restrict__ pairs, unsigned short* __restrict__ A1,
    unsigned int* __restrict__ bar) {
    __shared__ int tmp[256];
    const int bid = blockIdx.x, tid = threadIdx.x;
    const int gid0 = bid * 256 + tid;

    // ---- phase 0a: histogram (1 u64 atomic/edge: count<<32 | wfix) ----
    for (int e = gid0; e < N_EDGES; e += MEGA_GT) {
        int c = ei[N_EDGES + e];
        uint32_t wfix = (uint32_t)(ew[e] * DEG_SCALE + 0.5f);
        unsigned long long old =
            atomicAdd(&cnt64[c], (1ULL << 32) | (unsigned long long)wfix);
        rank[e] = (int)(old >> 32);
    }
    // ---- phase 0b: xb = bf16(x) (soaks BW while atomics drain) ----
    for (int i = gid0; i < N_NODES * IN_DIM / 4; i += MEGA_GT) {
        float4 v = ((const float4*)x)[i];
        uint32_t lo = (uint32_t)f32_to_bf16(v.x) | ((uint32_t)f32_to_bf16(v.y) << 16);
        uint32_t hi = (uint32_t)f32_to_bf16(v.z) | ((uint32_t)f32_to_bf16(v.w) << 16);
        ((uint2*)xb)[i] = make_uint2(lo, hi);
    }
    // ---- phase 0c: fragment-ordered weights (65536 shorts) ----
    // Frag order: short index = ((((nh*2+wc)*4+ks)*4+nt)*64+lane)*8 + j
    // W1F: value = W1[kk][row], row = nh*128+wc*64+nt*16+fr, kk = ks*32+fq*8+j
    // W2F: value = W2[kk][n],   n = wc*64+nt*16+fr,  kk = nh*128+ks*32+fq*8+j
    if (gid0 < 65536) {
        int idx = gid0 & 32767;
        int j = idx & 7, lane = (idx >> 3) & 63;
        int nt = (idx >> 9) & 3, ks = (idx >> 11) & 3;
        int wc = (idx >> 13) & 1, nh = (idx >> 14) & 1;
        int fr = lane & 15, fq = lane >> 4;
        if (gid0 < 32768) {
            int row = nh * 128 + wc * 64 + nt * 16 + fr;
            int kk = ks * 32 + fq * 8 + j;
            W1F[idx] = f32_to_bf16(W1[kk * HID_DIM + row]);
        } else {
            int n = wc * 64 + nt * 16 + fr;
            int kk = nh * 128 + ks * 32 + fq * 8 + j;
            W2F[idx] = f32_to_bf16(W2[kk * OUT_DIM + n]);
        }
    }
    grid_bar(&bar[0], MEGA_BLOCKS);

    // ---- phase 1: scan1 (blocks 0..390): block-exclusive count scan + dis ----
    if (bid < 391) {
        int i = bid * 256 + tid;
        unsigned long long cv = (i < N_NODES) ? cnt64[i] : 0ULL;
        int v = (int)(cv >> 32);
        tmp[tid] = v;
        __syncthreads();
        for (int off = 1; off < 256; off <<= 1) {
            int u = (tid >= off) ? tmp[tid - off] : 0;
            __syncthreads();
            tmp[tid] += u;
            __syncthreads();
        }
        if (i < N_NODES) {
            rowp[i] = tmp[tid] - v;          // exclusive
            uint32_t wf = (uint32_t)cv;
            dis[i] = wf ? rsqrtf((float)wf * DEG_INV) : 0.f;
        }
        if (tid == 255) bsums[bid] = tmp[255];
    }
    grid_bar(&bar[1], MEGA_BLOCKS);

    // ---- phase 2: per-block bsums-prefix reduce, finalize rowp ----
    if (bid < 391) {
        int s = 0;
        for (int i = tid; i < bid; i += 256) s += bsums[i];
        tmp[tid] = s;
        __syncthreads();
        for (int off = 128; off > 0; off >>= 1) {
            if (tid < off) tmp[tid] += tmp[tid + off];
            __syncthreads();
        }
        int pre = tmp[0];
        int i = bid * 256 + tid;
        if (i == 0) rowp[N_NODES] = N_EDGES;
        if (i < N_NODES) rowp[i] += pre;
    }
    grid_bar(&bar[2], MEGA_BLOCKS);

    // ---- phase 3: place (no atomics; writes normalized weight) ----
    for (int e = gid0; e < N_EDGES; e += MEGA_GT) {
        int s = ei[e];
        int c = ei[N_EDGES + e];
        int pos = rowp[c] + rank[e];
        float wn = ew[e] * dis[s] * dis[c];  // dis: 400KB, L2-resident
        pairs[pos] = make_int2(s, __float_as_int(wn));
    }
    grid_bar(&bar[3], MEGA_BLOCKS);

    // ---- phase 4: layer-1 aggregate: A1 = agg(xb) [bf16, no bias] ----
    for (int g = gid0; g < N_NODES * 16; g += MEGA_GT) {
        agg_node<true>((const uint4*)xb, rowp, pairs, A1, nullptr,
                       g >> 4, g & 15);
    }
}

// ---------------------------------------------------------------------------
// Standalone aggregate (layer 2, fp32 out + bias).
// ---------------------------------------------------------------------------
template <bool OUT_BF16>
__global__ void aggregate_kernel(const uint4* __restrict__ feat,
                                 const int* __restrict__ rowp,
                                 const int2* __restrict__ pairs,
                                 void* __restrict__ out_v,
                                 const float* __restrict__ bias) {
    int gtid = blockIdx.x * blockDim.x + threadIdx.x;
    int node = gtid >> 4;
    if (node >= N_NODES) return;
    agg_node<OUT_BF16>(feat, rowp, pairs, out_v, bias, node, threadIdx.x & 15);
}

// ---------------------------------------------------------------------------
// Fused 2-layer GEMM: T = relu(A @ W1 + b1) @ W2, bf16 in/out, fp32 acc.
// W streams are fragment-ordered (W1F/W2F) -> every wf load is one coalesced
// global_load_dwordx4; A-fragments hoisted to registers once (af[4][4]).
// LDS 66KB -> 2 blocks/CU; launch_bounds(256,2).
// ---------------------------------------------------------------------------
__global__ __launch_bounds__(256, 2) void gemm_fused_kernel(
    const unsigned short* __restrict__ A,     // [M][128] bf16
    const unsigned short* __restrict__ W1F,   // frag-ordered, 32768 shorts
    const float* __restrict__ b1,             // [256]
    const unsigned short* __restrict__ W2F,   // frag-ordered, 32768 shorts
    unsigned short* __restrict__ T,           // [M][128] bf16
    int M) {
    __shared__ unsigned short As[128 * 128];  // 32KB, chunk-swizzled
    __shared__ unsigned short Hs[128 * 136];  // 34KB, padded rows
    int tid = threadIdx.x;
    int wave = tid >> 6, lane = tid & 63;
    int m0 = blockIdx.x * 128;
    int wr = (wave & 1) * 64;
    int wcid = wave >> 1;
    int wc = wcid * 64;
    int fr = lane & 15, fq = lane >> 4;

    // stage A block: 2048 16B-chunks, 8 rounds of 256 lanes (XOR-swizzled)
    #pragma unroll
    for (int i = 0; i < 8; ++i) {
        int cbase = (i * 4 + wave) * 64;
        int c = cbase + lane;
        int m = c >> 4, cl = c & 15;
        int qg = ((cl & 7) ^ (m & 7)) | (cl & 8);
        int gm = m0 + m; if (gm >= M) gm = M - 1;
        const unsigned short* ga = A + (size_t)gm * 128 + qg * 8;
        __builtin_amdgcn_global_load_lds(
            (const __attribute__((address_space(1))) void*)ga,
            (__attribute__((address_space(3))) void*)(As + (size_t)cbase * 8),
            16, 0, 0);
    }
    __syncthreads();

    // A fragments to registers once; reused by both nh halves.
    bf16x8 af[4][4];   // [ks][mt]
    #pragma unroll
    for (int ks = 0; ks < 4; ++ks) {
        int q = ks * 4 + fq;
        int cl = ((q & 7) ^ (fr & 7)) | (q & 8);
        #pragma unroll
        for (int mt = 0; mt < 4; ++mt)
            af[ks][mt] = *(const bf16x8*)(As + (wr + mt * 16 + fr) * 128 + cl * 8);
    }

    const bf16x8* w1p = (const bf16x8*)W1F;
    const bf16x8* w2p = (const bf16x8*)W2F;

    f32x4 acc_t[4][4] = {};
    #pragma unroll
    for (int nh = 0; nh < 2; ++nh) {
        int wbase = (nh * 2 + wcid) * 16 * 64;   // 16 frags x 64 lanes per (nh,wc)
        // phase A: acc_h = A_tile @ W1[nh half]
        f32x4 acc_h[4][4] = {};
        #pragma unroll
        for (int ks = 0; ks < 4; ++ks) {
            bf16x8 wf[4];
            #pragma unroll
            for (int nt = 0; nt < 4; ++nt)
                wf[nt] = w1p[wbase + (ks * 4 + nt) * 64 + lane];
            #pragma unroll
            for (int mt = 0; mt < 4; ++mt)
                #pragma unroll
                for (int nt = 0; nt < 4; ++nt)
                    acc_h[mt][nt] = __builtin_amdgcn_mfma_f32_16x16x32_bf16(
                        af[ks][mt], wf[nt], acc_h[mt][nt], 0, 0, 0);
        }
        float bv[4];
        #pragma unroll
        for (int nt = 0; nt < 4; ++nt) bv[nt] = b1[nh * 128 + wc + nt * 16 + fr];
        __syncthreads();   // prior half's Hs consumers done
        #pragma unroll
        for (int mt = 0; mt < 4; ++mt)
            #pragma unroll
            for (int r = 0; r < 4; ++r) {
                int row = wr + mt * 16 + fq * 4 + r;
                #pragma unroll
                for (int nt = 0; nt < 4; ++nt) {
                    float v = fmaxf(acc_h[mt][nt][r] + bv[nt], 0.f);
                    Hs[row * 136 + wc + nt * 16 + fr] = f32_to_bf16(v);
                }
            }
        __syncthreads();   // Hs ready
        // phase B: acc_t += Hs @ W2[nh half rows]
        #pragma unroll
        for (int ks = 0; ks < 4; ++ks) {
            bf16x8 wf[4], hf[4];
            #pragma unroll
            for (int nt = 0; nt < 4; ++nt)
                wf[nt] = w2p[wbase + (ks * 4 + nt) * 64 + lane];
            #pragma unroll
            for (int mt = 0; mt < 4; ++mt)
                hf[mt] = *(const bf16x8*)(Hs + (wr + mt * 16 + fr) * 136 + ks * 32 + fq * 8);
            #pragma unroll
            for (int mt = 0; mt < 4; ++mt)
                #pragma unroll
                for (int nt = 0; nt < 4; ++nt)
                    acc_t[mt][nt] = __builtin_amdgcn_mfma_f32_16x16x32_bf16(
                        hf[mt], wf[nt], acc_t[mt][nt], 0, 0, 0);
        }
    }

    // epilogue: C/D layout col=lane&15, row=(lane>>4)*4+reg (m89-verified)
    #pragma unroll
    for (int mt = 0; mt < 4; ++mt)
        #pragma unroll
        for (int r = 0; r < 4; ++r) {
            int row = m0 + wr + mt * 16 + fq * 4 + r;
            if (row >= M) continue;
            #pragma unroll
            for (int nt = 0; nt < 4; ++nt)
                T[(size_t)row * 128 + wc + nt * 16 + fr] = f32_to_bf16(acc_t[mt][nt][r]);
        }
}

// ---------------------------------------------------------------------------
extern "C" void kernel_launch(void* const* d_in, const int* in_sizes, int n_in,
                              void* d_out, int out_size, void* d_ws, size_t ws_size,
                              hipStream_t stream) {
    const float* x  = (const float*)d_in[0];
    const int*   ei = (const int*)d_in[1];    // int32 (harness converts ints)
    const float* ew = (const float*)d_in[2];
    const float* W1 = (const float*)d_in[3];
    const float* b1 = (const float*)d_in[4];
    const float* W2 = (const float*)d_in[5];
    const float* b2 = (const float*)d_in[6];
    float* out = (float*)d_out;

    char* ws = (char*)d_ws;
    size_t off = 0;
    auto alloc = [&](size_t bytes) -> void* {
        void* p = ws + off;
        off = (off + bytes + 255) & ~(size_t)255;
        return p;
    };
    // bar + cnt64 contiguous so one memset zeroes both
    unsigned int* bar = (unsigned int*)alloc(256);
    unsigned long long* cnt64 = (unsigned long long*)alloc((size_t)N_NODES * 8);
    float* dis   = (float*)alloc((size_t)N_NODES * 4);
    int*   rowp  = (int*)  alloc((size_t)(N_NODES + 1) * 4);
    int*   bsums = (int*)  alloc(512 * 4);
    int*   rank  = (int*)  alloc((size_t)N_EDGES * 4);
    int2*  pairs = (int2*) alloc((size_t)N_EDGES * 8);
    uint32_t* xb = (uint32_t*)alloc((size_t)N_NODES * IN_DIM * 2);
    unsigned short* W1F = (unsigned short*)alloc((size_t)IN_DIM * HID_DIM * 2);
    unsigned short* W2F = (unsigned short*)alloc((size_t)HID_DIM * OUT_DIM * 2);
    unsigned short* A1  = (unsigned short*)alloc((size_t)N_NODES * IN_DIM * 2);
    unsigned short* t   = (unsigned short*)alloc((size_t)N_NODES * OUT_DIM * 2);

    hipMemsetAsync(bar, 0, 256 + (size_t)N_NODES * 8, stream);

    // mega: hist+prep -> scan1 -> scan23 -> place -> agg1 (manual barriers)
    mega_kernel<<<MEGA_BLOCKS, 256, 0, stream>>>(
        ei, ew, cnt64, rank, x, xb, W1, W1F, W2, W2F,
        rowp, bsums, dis, pairs, A1, bar);

    // fused dense stack: t = relu(A1 @ W1 + b1) @ W2  [bf16]
    gemm_fused_kernel<<<(N_NODES + 127) / 128, 256, 0, stream>>>(
        A1, W1F, b1, W2F, t, N_NODES);

    // layer 2 aggregate: out = agg(t) + b2 [fp32]
    int agg_blocks = (N_NODES * 16) / 256;   // 6250, exact
    aggregate_kernel<false><<<agg_blocks, 256, 0, stream>>>(
        (const uint4*)t, rowp, pairs, out, b2);
}

// Round 8
// 1225.220 us; speedup vs baseline: 1.0230x; 1.0230x over previous
//
#include <hip/hip_runtime.h>
#include <hip/hip_bf16.h>
#include <cstdint>
#include <cstddef>

#define N_NODES 100000
#define N_EDGES 800000
#define IN_DIM 128
#define HID_DIM 256
#define OUT_DIM 128

// deg fixed-point scale: 2^21. Max per-node wsum before low-word carry is
// 2^11 edges/node; random graph max-degree ~30. Per-edge quant error 2^-21.
#define DEG_SCALE 2097152.0f
#define DEG_INV   (1.0f / 2097152.0f)

// R15: 2048 blocks @ launch_bounds(256,8): the bound caps VGPR at 64 ->
// 8 blocks/CU GUARANTEED -> all 2048 co-resident -> barrier deadlock-free
// by construction. R7 failed because the 8-wide gather epoch (u[8]+p[8] =
// 48+ live regs) spilled to scratch under the 64-reg cap (VGPR=32 reported,
// +160MB scratch traffic, agg phase 10x). Mega agg phase is now WIDTH-4
// masked epochs (~40 live regs, fits with slack).
#define MEGA_BLOCKS 2048
#define MEGA_GT (MEGA_BLOCKS * 256)   // 524288 threads = full machine

typedef __attribute__((ext_vector_type(8))) short bf16x8;
typedef __attribute__((ext_vector_type(4))) float f32x4;

__device__ __forceinline__ unsigned short f32_to_bf16(float f) {
    __hip_bfloat16 b = __float2bfloat16(f);   // RNE
    return *reinterpret_cast<unsigned short*>(&b);
}
__device__ __forceinline__ float bf16_lo(uint32_t u) {
    uint32_t v = u << 16; return *reinterpret_cast<float*>(&v);
}
__device__ __forceinline__ float bf16_hi(uint32_t u) {
    uint32_t v = u & 0xffff0000u; return *reinterpret_cast<float*>(&v);
}

// ---------------------------------------------------------------------------
// Manual grid barrier — mechanism VALIDATED in R6 (passed, absmax == base).
// Device-scope atomics + __threadfence per G16; one counter per barrier
// instance (memset-zeroed each launch). s_sleep(32) (~2048 cyc) keeps the
// 2048 pollers' cross-XCD probe traffic ~100 GB/s-scale (R7 used s_sleep(2);
// at 2048 pollers that is ~2 TB/s of single-line probes during skew).
// ---------------------------------------------------------------------------
__device__ __forceinline__ void grid_bar(unsigned int* b, unsigned int n) {
    __syncthreads();
    if (threadIdx.x == 0) {
        __threadfence();                               // release my stores
        atomicAdd(b, 1u);                              // device-scope arrive
        while (__hip_atomic_load(b, __ATOMIC_RELAXED,
                                 __HIP_MEMORY_SCOPE_AGENT) < n)
            __builtin_amdgcn_s_sleep(32);
        __threadfence();                               // acquire others' stores
    }
    __syncthreads();
}

// ---------------------------------------------------------------------------
// Edge accumulate: 8 bf16 dims from one uint4.
// ---------------------------------------------------------------------------
__device__ __forceinline__ void acc_edge(float w, uint4 u, float* a) {
    a[0] += w * bf16_lo(u.x); a[1] += w * bf16_hi(u.x);
    a[2] += w * bf16_lo(u.y); a[3] += w * bf16_hi(u.y);
    a[4] += w * bf16_lo(u.z); a[5] += w * bf16_hi(u.z);
    a[6] += w * bf16_lo(u.w); a[7] += w * bf16_hi(u.w);
}

// ---------------------------------------------------------------------------
// Full-width (unroll 8) aggregate body — used ONLY by the standalone
// aggregate kernel (no register cap there). 16 lanes/node, uint4/lane.
// ---------------------------------------------------------------------------
template <bool OUT_BF16>
__device__ __forceinline__ void agg_node(const uint4* __restrict__ feat,
                                         const int* __restrict__ rowp,
                                         const int2* __restrict__ pairs,
                                         void* __restrict__ out_v,
                                         const float* __restrict__ bias,
                                         int node, int lane) {
    int beg = rowp[node], end = rowp[node + 1];
    float a[8] = {};

    int j = beg;
    for (; j + 8 <= end; j += 8) {
        int2 p[8]; uint4 u[8];
        #pragma unroll
        for (int q = 0; q < 8; ++q) p[q] = pairs[j + q];
        #pragma unroll
        for (int q = 0; q < 8; ++q) u[q] = feat[(size_t)p[q].x * 16 + lane];
        #pragma unroll
        for (int q = 0; q < 8; ++q) acc_edge(__int_as_float(p[q].y), u[q], a);
    }
    int r = end - j;
    if (r > 4) {
        int2 p[8]; uint4 u[8];
        #pragma unroll
        for (int q = 0; q < 8; ++q) p[q] = pairs[(j + q < end) ? j + q : end - 1];
        #pragma unroll
        for (int q = 0; q < 8; ++q) u[q] = feat[(size_t)p[q].x * 16 + lane];
        #pragma unroll
        for (int q = 0; q < 8; ++q) {
            float w = (j + q < end) ? __int_as_float(p[q].y) : 0.f;
            acc_edge(w, u[q], a);
        }
    } else if (r > 0) {
        int2 p[4]; uint4 u[4];
        #pragma unroll
        for (int q = 0; q < 4; ++q) p[q] = pairs[(j + q < end) ? j + q : end - 1];
        #pragma unroll
        for (int q = 0; q < 4; ++q) u[q] = feat[(size_t)p[q].x * 16 + lane];
        #pragma unroll
        for (int q = 0; q < 4; ++q) {
            float w = (j + q < end) ? __int_as_float(p[q].y) : 0.f;
            acc_edge(w, u[q], a);
        }
    }

    if (bias) {
        float4 b0 = ((const float4*)bias)[lane * 2];
        float4 b1 = ((const float4*)bias)[lane * 2 + 1];
        a[0] += b0.x; a[1] += b0.y; a[2] += b0.z; a[3] += b0.w;
        a[4] += b1.x; a[5] += b1.y; a[6] += b1.z; a[7] += b1.w;
    }
    if (OUT_BF16) {
        uint4 o;
        o.x = (uint32_t)f32_to_bf16(a[0]) | ((uint32_t)f32_to_bf16(a[1]) << 16);
        o.y = (uint32_t)f32_to_bf16(a[2]) | ((uint32_t)f32_to_bf16(a[3]) << 16);
        o.z = (uint32_t)f32_to_bf16(a[4]) | ((uint32_t)f32_to_bf16(a[5]) << 16);
        o.w = (uint32_t)f32_to_bf16(a[6]) | ((uint32_t)f32_to_bf16(a[7]) << 16);
        ((uint4*)out_v)[(size_t)node * 16 + lane] = o;
    } else {
        ((float4*)out_v)[(size_t)node * 32 + lane * 2] =
            make_float4(a[0], a[1], a[2], a[3]);
        ((float4*)out_v)[(size_t)node * 32 + lane * 2 + 1] =
            make_float4(a[4], a[5], a[6], a[7]);
    }
}

// ---------------------------------------------------------------------------
// Mega-kernel = hist+prep -> scan1 -> scan23 -> place -> agg1 with manual
// device-scope barriers. launch_bounds(256,8) => VGPR<=64 => 2048 blocks
// co-resident (deadlock-free). All register-hungry code paths kept <=~40
// live regs (width-4 agg) to avoid R7's scratch-spill catastrophe.
// ---------------------------------------------------------------------------
__global__ __launch_bounds__(256, 8) void mega_kernel(
    const int* __restrict__ ei, const float* __restrict__ ew,
    unsigned long long* __restrict__ cnt64, int* __restrict__ rank,
    const float* __restrict__ x, uint32_t* __restrict__ xb,
    const float* __restrict__ W1, unsigned short* __restrict__ W1F,
    const float* __restrict__ W2, unsigned short* __restrict__ W2F,
    int* __restrict__ rowp, int* __restrict__ bsums, float* __restrict__ dis,
    int2* __restrict__ pairs, unsigned short* __restrict__ A1,
    unsigned int* __restrict__ bar) {
    __shared__ int tmp[256];
    const int bid = blockIdx.x, tid = threadIdx.x;
    const int gid0 = bid * 256 + tid;

    // ---- phase 0a: histogram (1 u64 atomic/edge: count<<32 | wfix) ----
    for (int e = gid0; e < N_EDGES; e += MEGA_GT) {
        int c = ei[N_EDGES + e];
        uint32_t wfix = (uint32_t)(ew[e] * DEG_SCALE + 0.5f);
        unsigned long long old =
            atomicAdd(&cnt64[c], (1ULL << 32) | (unsigned long long)wfix);
        rank[e] = (int)(old >> 32);
    }
    // ---- phase 0b: xb = bf16(x) (soaks BW while atomics drain) ----
    for (int i = gid0; i < N_NODES * IN_DIM / 4; i += MEGA_GT) {
        float4 v = ((const float4*)x)[i];
        uint32_t lo = (uint32_t)f32_to_bf16(v.x) | ((uint32_t)f32_to_bf16(v.y) << 16);
        uint32_t hi = (uint32_t)f32_to_bf16(v.z) | ((uint32_t)f32_to_bf16(v.w) << 16);
        ((uint2*)xb)[i] = make_uint2(lo, hi);
    }
    // ---- phase 0c: fragment-ordered weights (65536 shorts) ----
    // Frag order: short index = ((((nh*2+wc)*4+ks)*4+nt)*64+lane)*8 + j
    // W1F: value = W1[kk][row], row = nh*128+wc*64+nt*16+fr, kk = ks*32+fq*8+j
    // W2F: value = W2[kk][n],   n = wc*64+nt*16+fr,  kk = nh*128+ks*32+fq*8+j
    if (gid0 < 65536) {
        int idx = gid0 & 32767;
        int j = idx & 7, lane = (idx >> 3) & 63;
        int nt = (idx >> 9) & 3, ks = (idx >> 11) & 3;
        int wc = (idx >> 13) & 1, nh = (idx >> 14) & 1;
        int fr = lane & 15, fq = lane >> 4;
        if (gid0 < 32768) {
            int row = nh * 128 + wc * 64 + nt * 16 + fr;
            int kk = ks * 32 + fq * 8 + j;
            W1F[idx] = f32_to_bf16(W1[kk * HID_DIM + row]);
        } else {
            int n = wc * 64 + nt * 16 + fr;
            int kk = nh * 128 + ks * 32 + fq * 8 + j;
            W2F[idx] = f32_to_bf16(W2[kk * OUT_DIM + n]);
        }
    }
    grid_bar(&bar[0], MEGA_BLOCKS);

    // ---- phase 1: scan1 (blocks 0..390): block-exclusive count scan + dis ----
    if (bid < 391) {
        int i = bid * 256 + tid;
        unsigned long long cv = (i < N_NODES) ? cnt64[i] : 0ULL;
        int v = (int)(cv >> 32);
        tmp[tid] = v;
        __syncthreads();
        for (int off = 1; off < 256; off <<= 1) {
            int u = (tid >= off) ? tmp[tid - off] : 0;
            __syncthreads();
            tmp[tid] += u;
            __syncthreads();
        }
        if (i < N_NODES) {
            rowp[i] = tmp[tid] - v;          // exclusive
            uint32_t wf = (uint32_t)cv;
            dis[i] = wf ? rsqrtf((float)wf * DEG_INV) : 0.f;
        }
        if (tid == 255) bsums[bid] = tmp[255];
    }
    grid_bar(&bar[1], MEGA_BLOCKS);

    // ---- phase 2: per-block bsums-prefix reduce, finalize rowp ----
    if (bid < 391) {
        int s = 0;
        for (int i = tid; i < bid; i += 256) s += bsums[i];
        tmp[tid] = s;
        __syncthreads();
        for (int off = 128; off > 0; off >>= 1) {
            if (tid < off) tmp[tid] += tmp[tid + off];
            __syncthreads();
        }
        int pre = tmp[0];
        int i = bid * 256 + tid;
        if (i == 0) rowp[N_NODES] = N_EDGES;
        if (i < N_NODES) rowp[i] += pre;
    }
    grid_bar(&bar[2], MEGA_BLOCKS);

    // ---- phase 3: place (no atomics; writes normalized weight) ----
    for (int e = gid0; e < N_EDGES; e += MEGA_GT) {
        int s = ei[e];
        int c = ei[N_EDGES + e];
        int pos = rowp[c] + rank[e];
        float wn = ew[e] * dis[s] * dis[c];  // dis: 400KB, L2-resident
        pairs[pos] = make_int2(s, __float_as_int(wn));
    }
    grid_bar(&bar[3], MEGA_BLOCKS);

    // ---- phase 4: layer-1 aggregate: A1 = agg(xb), WIDTH-4 masked epochs
    //      (register-light: ~40 live regs, no spill under the 64-reg cap) ----
    for (int g = gid0; g < N_NODES * 16; g += MEGA_GT) {
        int node = g >> 4, lane = g & 15;
        int beg = rowp[node], end = rowp[node + 1];
        float a[8] = {};
        for (int j = beg; j < end; j += 4) {
            int2 p[4]; uint4 u[4];
            #pragma unroll
            for (int q = 0; q < 4; ++q)
                p[q] = pairs[(j + q < end) ? j + q : end - 1];
            #pragma unroll
            for (int q = 0; q < 4; ++q)
                u[q] = ((const uint4*)xb)[(size_t)p[q].x * 16 + lane];
            #pragma unroll
            for (int q = 0; q < 4; ++q) {
                float w = (j + q < end) ? __int_as_float(p[q].y) : 0.f;
                acc_edge(w, u[q], a);
            }
        }
        uint4 o;
        o.x = (uint32_t)f32_to_bf16(a[0]) | ((uint32_t)f32_to_bf16(a[1]) << 16);
        o.y = (uint32_t)f32_to_bf16(a[2]) | ((uint32_t)f32_to_bf16(a[3]) << 16);
        o.z = (uint32_t)f32_to_bf16(a[4]) | ((uint32_t)f32_to_bf16(a[5]) << 16);
        o.w = (uint32_t)f32_to_bf16(a[6]) | ((uint32_t)f32_to_bf16(a[7]) << 16);
        ((uint4*)A1)[(size_t)node * 16 + lane] = o;
    }
}

// ---------------------------------------------------------------------------
// Standalone aggregate (layer 2, fp32 out + bias) — unconstrained registers.
// ---------------------------------------------------------------------------
template <bool OUT_BF16>
__global__ void aggregate_kernel(const uint4* __restrict__ feat,
                                 const int* __restrict__ rowp,
                                 const int2* __restrict__ pairs,
                                 void* __restrict__ out_v,
                                 const float* __restrict__ bias) {
    int gtid = blockIdx.x * blockDim.x + threadIdx.x;
    int node = gtid >> 4;
    if (node >= N_NODES) return;
    agg_node<OUT_BF16>(feat, rowp, pairs, out_v, bias, node, threadIdx.x & 15);
}

// ---------------------------------------------------------------------------
// Fused 2-layer GEMM: T = relu(A @ W1 + b1) @ W2, bf16 in/out, fp32 acc.
// W streams are fragment-ordered (W1F/W2F) -> every wf load is one coalesced
// global_load_dwordx4; A-fragments hoisted to registers once (af[4][4]).
// LDS 66KB -> 2 blocks/CU; launch_bounds(256,2).
// ---------------------------------------------------------------------------
__global__ __launch_bounds__(256, 2) void gemm_fused_kernel(
    const unsigned short* __restrict__ A,     // [M][128] bf16
    const unsigned short* __restrict__ W1F,   // frag-ordered, 32768 shorts
    const float* __restrict__ b1,             // [256]
    const unsigned short* __restrict__ W2F,   // frag-ordered, 32768 shorts
    unsigned short* __restrict__ T,           // [M][128] bf16
    int M) {
    __shared__ unsigned short As[128 * 128];  // 32KB, chunk-swizzled
    __shared__ unsigned short Hs[128 * 136];  // 34KB, padded rows
    int tid = threadIdx.x;
    int wave = tid >> 6, lane = tid & 63;
    int m0 = blockIdx.x * 128;
    int wr = (wave & 1) * 64;
    int wcid = wave >> 1;
    int wc = wcid * 64;
    int fr = lane & 15, fq = lane >> 4;

    // stage A block: 2048 16B-chunks, 8 rounds of 256 lanes (XOR-swizzled)
    #pragma unroll
    for (int i = 0; i < 8; ++i) {
        int cbase = (i * 4 + wave) * 64;
        int c = cbase + lane;
        int m = c >> 4, cl = c & 15;
        int qg = ((cl & 7) ^ (m & 7)) | (cl & 8);
        int gm = m0 + m; if (gm >= M) gm = M - 1;
        const unsigned short* ga = A + (size_t)gm * 128 + qg * 8;
        __builtin_amdgcn_global_load_lds(
            (const __attribute__((address_space(1))) void*)ga,
            (__attribute__((address_space(3))) void*)(As + (size_t)cbase * 8),
            16, 0, 0);
    }
    __syncthreads();

    // A fragments to registers once; reused by both nh halves.
    bf16x8 af[4][4];   // [ks][mt]
    #pragma unroll
    for (int ks = 0; ks < 4; ++ks) {
        int q = ks * 4 + fq;
        int cl = ((q & 7) ^ (fr & 7)) | (q & 8);
        #pragma unroll
        for (int mt = 0; mt < 4; ++mt)
            af[ks][mt] = *(const bf16x8*)(As + (wr + mt * 16 + fr) * 128 + cl * 8);
    }

    const bf16x8* w1p = (const bf16x8*)W1F;
    const bf16x8* w2p = (const bf16x8*)W2F;

    f32x4 acc_t[4][4] = {};
    #pragma unroll
    for (int nh = 0; nh < 2; ++nh) {
        int wbase = (nh * 2 + wcid) * 16 * 64;   // 16 frags x 64 lanes per (nh,wc)
        // phase A: acc_h = A_tile @ W1[nh half]
        f32x4 acc_h[4][4] = {};
        #pragma unroll
        for (int ks = 0; ks < 4; ++ks) {
            bf16x8 wf[4];
            #pragma unroll
            for (int nt = 0; nt < 4; ++nt)
                wf[nt] = w1p[wbase + (ks * 4 + nt) * 64 + lane];
            #pragma unroll
            for (int mt = 0; mt < 4; ++mt)
                #pragma unroll
                for (int nt = 0; nt < 4; ++nt)
                    acc_h[mt][nt] = __builtin_amdgcn_mfma_f32_16x16x32_bf16(
                        af[ks][mt], wf[nt], acc_h[mt][nt], 0, 0, 0);
        }
        float bv[4];
        #pragma unroll
        for (int nt = 0; nt < 4; ++nt) bv[nt] = b1[nh * 128 + wc + nt * 16 + fr];
        __syncthreads();   // prior half's Hs consumers done
        #pragma unroll
        for (int mt = 0; mt < 4; ++mt)
            #pragma unroll
            for (int r = 0; r < 4; ++r) {
                int row = wr + mt * 16 + fq * 4 + r;
                #pragma unroll
                for (int nt = 0; nt < 4; ++nt) {
                    float v = fmaxf(acc_h[mt][nt][r] + bv[nt], 0.f);
                    Hs[row * 136 + wc + nt * 16 + fr] = f32_to_bf16(v);
                }
            }
        __syncthreads();   // Hs ready
        // phase B: acc_t += Hs @ W2[nh half rows]
        #pragma unroll
        for (int ks = 0; ks < 4; ++ks) {
            bf16x8 wf[4], hf[4];
            #pragma unroll
            for (int nt = 0; nt < 4; ++nt)
                wf[nt] = w2p[wbase + (ks * 4 + nt) * 64 + lane];
            #pragma unroll
            for (int mt = 0; mt < 4; ++mt)
                hf[mt] = *(const bf16x8*)(Hs + (wr + mt * 16 + fr) * 136 + ks * 32 + fq * 8);
            #pragma unroll
            for (int mt = 0; mt < 4; ++mt)
                #pragma unroll
                for (int nt = 0; nt < 4; ++nt)
                    acc_t[mt][nt] = __builtin_amdgcn_mfma_f32_16x16x32_bf16(
                        hf[mt], wf[nt], acc_t[mt][nt], 0, 0, 0);
        }
    }

    // epilogue: C/D layout col=lane&15, row=(lane>>4)*4+reg (m89-verified)
    #pragma unroll
    for (int mt = 0; mt < 4; ++mt)
        #pragma unroll
        for (int r = 0; r < 4; ++r) {
            int row = m0 + wr + mt * 16 + fq * 4 + r;
            if (row >= M) continue;
            #pragma unroll
            for (int nt = 0; nt < 4; ++nt)
                T[(size_t)row * 128 + wc + nt * 16 + fr] = f32_to_bf16(acc_t[mt][nt][r]);
        }
}

// ---------------------------------------------------------------------------
extern "C" void kernel_launch(void* const* d_in, const int* in_sizes, int n_in,
                              void* d_out, int out_size, void* d_ws, size_t ws_size,
                              hipStream_t stream) {
    const float* x  = (const float*)d_in[0];
    const int*   ei = (const int*)d_in[1];    // int32 (harness converts ints)
    const float* ew = (const float*)d_in[2];
    const float* W1 = (const float*)d_in[3];
    const float* b1 = (const float*)d_in[4];
    const float* W2 = (const float*)d_in[5];
    const float* b2 = (const float*)d_in[6];
    float* out = (float*)d_out;

    char* ws = (char*)d_ws;
    size_t off = 0;
    auto alloc = [&](size_t bytes) -> void* {
        void* p = ws + off;
        off = (off + bytes + 255) & ~(size_t)255;
        return p;
    };
    // bar + cnt64 contiguous so one memset zeroes both
    unsigned int* bar = (unsigned int*)alloc(256);
    unsigned long long* cnt64 = (unsigned long long*)alloc((size_t)N_NODES * 8);
    float* dis   = (float*)alloc((size_t)N_NODES * 4);
    int*   rowp  = (int*)  alloc((size_t)(N_NODES + 1) * 4);
    int*   bsums = (int*)  alloc(512 * 4);
    int*   rank  = (int*)  alloc((size_t)N_EDGES * 4);
    int2*  pairs = (int2*) alloc((size_t)N_EDGES * 8);
    uint32_t* xb = (uint32_t*)alloc((size_t)N_NODES * IN_DIM * 2);
    unsigned short* W1F = (unsigned short*)alloc((size_t)IN_DIM * HID_DIM * 2);
    unsigned short* W2F = (unsigned short*)alloc((size_t)HID_DIM * OUT_DIM * 2);
    unsigned short* A1  = (unsigned short*)alloc((size_t)N_NODES * IN_DIM * 2);
    unsigned short* t   = (unsigned short*)alloc((size_t)N_NODES * OUT_DIM * 2);

    hipMemsetAsync(bar, 0, 256 + (size_t)N_NODES * 8, stream);

    // mega: hist+prep -> scan1 -> scan23 -> place -> agg1 (manual barriers)
    mega_kernel<<<MEGA_BLOCKS, 256, 0, stream>>>(
        ei, ew, cnt64, rank, x, xb, W1, W1F, W2, W2F,
        rowp, bsums, dis, pairs, A1, bar);

    // fused dense stack: t = relu(A1 @ W1 + b1) @ W2  [bf16]
    gemm_fused_kernel<<<(N_NODES + 127) / 128, 256, 0, stream>>>(
        A1, W1F, b1, W2F, t, N_NODES);

    // layer 2 aggregate: out = agg(t) + b2 [fp32]
    int agg_blocks = (N_NODES * 16) / 256;   // 6250, exact
    aggregate_kernel<false><<<agg_blocks, 256, 0, stream>>>(
        (const uint4*)t, rowp, pairs, out, b2);
}

// Round 9
// 282.170 us; speedup vs baseline: 4.4421x; 4.3421x over previous
//
#include <hip/hip_runtime.h>
#include <hip/hip_bf16.h>
#include <cstdint>
#include <cstddef>

#define N_NODES 100000
#define N_EDGES 800000
#define IN_DIM 128
#define HID_DIM 256
#define OUT_DIM 128

// deg fixed-point scale: 2^21. Max per-node wsum before low-word carry is
// 2^11 edges/node; random graph max-degree ~30. Per-edge quant error 2^-21.
#define DEG_SCALE 2097152.0f
#define DEG_INV   (1.0f / 2097152.0f)

typedef __attribute__((ext_vector_type(8))) short bf16x8;
typedef __attribute__((ext_vector_type(4))) float f32x4;

__device__ __forceinline__ unsigned short f32_to_bf16(float f) {
    __hip_bfloat16 b = __float2bfloat16(f);   // RNE
    return *reinterpret_cast<unsigned short*>(&b);
}
__device__ __forceinline__ float bf16_lo(uint32_t u) {
    uint32_t v = u << 16; return *reinterpret_cast<float*>(&v);
}
__device__ __forceinline__ float bf16_hi(uint32_t u) {
    uint32_t v = u & 0xffff0000u; return *reinterpret_cast<float*>(&v);
}

// ---------------------------------------------------------------------------
// R16: REVERT to the R4 multi-launch structure (274.6us, every phase
// measured; mega/manual-grid-barrier abandoned per R7 pre-commitment —
// R6/R7/R8 showed its cost scales with block count, machine idle at 97%
// occupancy, unexplained by spill or traffic). Single change vs R4:
// agg1 is FUSED into the GEMM staging phase (saves the agg1 launch, its
// 25.6MB A1 write + 25.6MB A1 read, and one launch gap).
// ---------------------------------------------------------------------------
#define HIST_BLOCKS 3125    // 3125*256 == 800000 exactly
#define XB_BLOCKS 12500     // 12500*256*4 == 100000*128

__global__ void hist_prep_kernel(const int* __restrict__ ei,
                                 const float* __restrict__ ew,
                                 unsigned long long* __restrict__ cnt64,
                                 int* __restrict__ rank,
                                 const float* __restrict__ x,
                                 uint32_t* __restrict__ xb,
                                 const float* __restrict__ W1,
                                 unsigned short* __restrict__ W1F,
                                 const float* __restrict__ W2,
                                 unsigned short* __restrict__ W2F) {
    int b = blockIdx.x;
    if (b < HIST_BLOCKS) {
        int e = b * 256 + threadIdx.x;
        int c = ei[N_EDGES + e];
        uint32_t wfix = (uint32_t)(ew[e] * DEG_SCALE + 0.5f);
        unsigned long long add = (1ULL << 32) | (unsigned long long)wfix;
        unsigned long long old = atomicAdd(&cnt64[c], add);
        rank[e] = (int)(old >> 32);
        return;
    }
    b -= HIST_BLOCKS;
    if (b < XB_BLOCKS) {                               // xb = bf16(x)
        int i = b * 256 + threadIdx.x;
        float4 v = ((const float4*)x)[i];
        uint32_t lo = (uint32_t)f32_to_bf16(v.x) | ((uint32_t)f32_to_bf16(v.y) << 16);
        uint32_t hi = (uint32_t)f32_to_bf16(v.z) | ((uint32_t)f32_to_bf16(v.w) << 16);
        ((uint2*)xb)[i] = make_uint2(lo, hi);
    } else if (b < XB_BLOCKS + 128) {                  // W1F: 32768 shorts
        int idx = (b - XB_BLOCKS) * 256 + threadIdx.x;
        int j = idx & 7, lane = (idx >> 3) & 63;
        int nt = (idx >> 9) & 3, ks = (idx >> 11) & 3;
        int wc = (idx >> 13) & 1, nh = (idx >> 14) & 1;
        int fr = lane & 15, fq = lane >> 4;
        int row = nh * 128 + wc * 64 + nt * 16 + fr;
        int kk = ks * 32 + fq * 8 + j;
        W1F[idx] = f32_to_bf16(W1[kk * HID_DIM + row]);
    } else {                                           // W2F: 32768 shorts
        int idx = (b - XB_BLOCKS - 128) * 256 + threadIdx.x;
        int j = idx & 7, lane = (idx >> 3) & 63;
        int nt = (idx >> 9) & 3, ks = (idx >> 11) & 3;
        int wc = (idx >> 13) & 1, nh = (idx >> 14) & 1;
        int fr = lane & 15, fq = lane >> 4;
        int n = wc * 64 + nt * 16 + fr;
        int kk = nh * 128 + ks * 32 + fq * 8 + j;
        W2F[idx] = f32_to_bf16(W2[kk * OUT_DIM + n]);
    }
}

// scan1: block-exclusive scan of counts (high words); also emits dis from
// the packed weight sums (low words).
__global__ void scan1_kernel(const unsigned long long* __restrict__ cnt64,
                             int* __restrict__ out, int* __restrict__ bsums,
                             float* __restrict__ dis, int n) {
    __shared__ int tmp[256];
    int t = threadIdx.x;
    int i = blockIdx.x * 256 + t;
    unsigned long long cv = (i < n) ? cnt64[i] : 0ULL;
    int v = (int)(cv >> 32);
    tmp[t] = v;
    __syncthreads();
    for (int off = 1; off < 256; off <<= 1) {
        int u = (t >= off) ? tmp[t - off] : 0;
        __syncthreads();
        tmp[t] += u;
        __syncthreads();
    }
    if (i < n) {
        out[i] = tmp[t] - v;                 // exclusive
        uint32_t wf = (uint32_t)cv;
        dis[i] = wf ? rsqrtf((float)wf * DEG_INV) : 0.f;
    }
    if (t == 255) bsums[blockIdx.x] = tmp[255];
}

// scan2+scan3 fused: each block reduces its own bsums prefix (<=391 ints).
__global__ void scan23_kernel(int* __restrict__ rowp, const int* __restrict__ bsums,
                              int n, int total) {
    __shared__ int red[256];
    int b = blockIdx.x, t = threadIdx.x;
    int s = 0;
    for (int i = t; i < b; i += 256) s += bsums[i];
    red[t] = s;
    __syncthreads();
    for (int off = 128; off > 0; off >>= 1) {
        if (t < off) red[t] += red[t + off];
        __syncthreads();
    }
    int pre = red[0];
    int i = b * 256 + t;
    if (i == 0) rowp[n] = total;
    if (i < n) rowp[i] += pre;
}

// place: no atomics — slot = rowp[col] + rank[e]. Writes the FULLY
// NORMALIZED weight (dis ready since scan1); aggregates skip dis.
__global__ void place_kernel(const int* __restrict__ ei,
                             const float* __restrict__ ew,
                             const int* __restrict__ rank,
                             const int* __restrict__ rowp,
                             const float* __restrict__ dis,
                             int2* __restrict__ pairs) {
    int e = blockIdx.x * 256 + threadIdx.x;
    if (e >= N_EDGES) return;
    int s = ei[e];
    int c = ei[N_EDGES + e];
    int pos = rowp[c] + rank[e];
    float wn = ew[e] * dis[s] * dis[c];      // dis: 400KB, L2-resident
    pairs[pos] = make_int2(s, __float_as_int(wn));
}

// ---------------------------------------------------------------------------
// Edge accumulate: 8 bf16 dims from one uint4.
// ---------------------------------------------------------------------------
__device__ __forceinline__ void acc_edge(float w, uint4 u, float* a) {
    a[0] += w * bf16_lo(u.x); a[1] += w * bf16_hi(u.x);
    a[2] += w * bf16_lo(u.y); a[3] += w * bf16_hi(u.y);
    a[4] += w * bf16_lo(u.z); a[5] += w * bf16_hi(u.z);
    a[6] += w * bf16_lo(u.w); a[7] += w * bf16_hi(u.w);
}

// ---------------------------------------------------------------------------
// Standalone aggregate (layer 2): 16 lanes/node, uint4/lane, unroll 8 +
// masked tail epochs (R4-passing version).
// ---------------------------------------------------------------------------
template <bool OUT_BF16>
__global__ void aggregate_kernel(const uint4* __restrict__ feat,
                                 const int* __restrict__ rowp,
                                 const int2* __restrict__ pairs,
                                 void* __restrict__ out_v,
                                 const float* __restrict__ bias) {
    int gtid = blockIdx.x * blockDim.x + threadIdx.x;
    int node = gtid >> 4;
    int lane = threadIdx.x & 15;
    if (node >= N_NODES) return;
    int beg = rowp[node], end = rowp[node + 1];
    float a[8] = {};

    int j = beg;
    for (; j + 8 <= end; j += 8) {
        int2 p[8]; uint4 u[8];
        #pragma unroll
        for (int q = 0; q < 8; ++q) p[q] = pairs[j + q];
        #pragma unroll
        for (int q = 0; q < 8; ++q) u[q] = feat[(size_t)p[q].x * 16 + lane];
        #pragma unroll
        for (int q = 0; q < 8; ++q) acc_edge(__int_as_float(p[q].y), u[q], a);
    }
    int r = end - j;
    if (r > 4) {
        int2 p[8]; uint4 u[8];
        #pragma unroll
        for (int q = 0; q < 8; ++q) p[q] = pairs[(j + q < end) ? j + q : end - 1];
        #pragma unroll
        for (int q = 0; q < 8; ++q) u[q] = feat[(size_t)p[q].x * 16 + lane];
        #pragma unroll
        for (int q = 0; q < 8; ++q) {
            float w = (j + q < end) ? __int_as_float(p[q].y) : 0.f;
            acc_edge(w, u[q], a);
        }
    } else if (r > 0) {
        int2 p[4]; uint4 u[4];
        #pragma unroll
        for (int q = 0; q < 4; ++q) p[q] = pairs[(j + q < end) ? j + q : end - 1];
        #pragma unroll
        for (int q = 0; q < 4; ++q) u[q] = feat[(size_t)p[q].x * 16 + lane];
        #pragma unroll
        for (int q = 0; q < 4; ++q) {
            float w = (j + q < end) ? __int_as_float(p[q].y) : 0.f;
            acc_edge(w, u[q], a);
        }
    }

    if (bias) {
        float4 b0 = ((const float4*)bias)[lane * 2];
        float4 b1 = ((const float4*)bias)[lane * 2 + 1];
        a[0] += b0.x; a[1] += b0.y; a[2] += b0.z; a[3] += b0.w;
        a[4] += b1.x; a[5] += b1.y; a[6] += b1.z; a[7] += b1.w;
    }
    if (OUT_BF16) {
        uint4 o;
        o.x = (uint32_t)f32_to_bf16(a[0]) | ((uint32_t)f32_to_bf16(a[1]) << 16);
        o.y = (uint32_t)f32_to_bf16(a[2]) | ((uint32_t)f32_to_bf16(a[3]) << 16);
        o.z = (uint32_t)f32_to_bf16(a[4]) | ((uint32_t)f32_to_bf16(a[5]) << 16);
        o.w = (uint32_t)f32_to_bf16(a[6]) | ((uint32_t)f32_to_bf16(a[7]) << 16);
        ((uint4*)out_v)[(size_t)node * 16 + lane] = o;
    } else {
        ((float4*)out_v)[(size_t)node * 32 + lane * 2] =
            make_float4(a[0], a[1], a[2], a[3]);
        ((float4*)out_v)[(size_t)node * 32 + lane * 2 + 1] =
            make_float4(a[4], a[5], a[6], a[7]);
    }
}

// ---------------------------------------------------------------------------
// Fused aggregate + 2-layer GEMM: T = relu(agg(xb) @ W1 + b1) @ W2.
// R16: the staging phase gathers-and-aggregates each block's 128 node rows
// DIRECTLY into As (replaces A1 materialization + global_load_lds re-read).
// 16 lanes/node, width-4 masked gather epochs; result stored bf16 into the
// XOR-swizzled LDS layout: lane's global chunk l lands at cl=((l&7)^(m&7))
// |(l&8), which the fragment loader (cl=((q&7)^(fr&7))|(q&8)) inverts.
// W streams fragment-ordered; A-fragments hoisted once; LDS 66KB ->
// 2 blocks/CU so block k+1's gathers overlap block k's MFMA.
// ---------------------------------------------------------------------------
__global__ __launch_bounds__(256, 2) void gemm_agg_fused_kernel(
    const uint32_t* __restrict__ xb,          // [N][128] bf16 features
    const int* __restrict__ rowp,
    const int2* __restrict__ pairs,
    const unsigned short* __restrict__ W1F,   // frag-ordered, 32768 shorts
    const float* __restrict__ b1,             // [256]
    const unsigned short* __restrict__ W2F,   // frag-ordered, 32768 shorts
    unsigned short* __restrict__ T,           // [M][128] bf16
    int M) {
    __shared__ __align__(16) unsigned short As[128 * 128];  // 32KB, swizzled
    __shared__ unsigned short Hs[128 * 136];  // 34KB, padded rows
    int tid = threadIdx.x;
    int wave = tid >> 6, lane = tid & 63;
    int m0 = blockIdx.x * 128;
    int wr = (wave & 1) * 64;
    int wcid = wave >> 1;
    int wc = wcid * 64;
    int fr = lane & 15, fq = lane >> 4;

    // ---- staging: gather-aggregate 128 rows (8 rounds x 16 nodes) ----
    {
        int glane = tid & 15;                 // dims glane*8 .. glane*8+7
        #pragma unroll
        for (int rnd = 0; rnd < 8; ++rnd) {
            int m = rnd * 16 + (tid >> 4);    // row within block, 0..127
            int node = m0 + m; if (node >= M) node = M - 1;
            int beg = rowp[node], end = rowp[node + 1];
            float a[8] = {};
            for (int j = beg; j < end; j += 4) {
                int2 p[4]; uint4 u[4];
                #pragma unroll
                for (int q = 0; q < 4; ++q)
                    p[q] = pairs[(j + q < end) ? j + q : end - 1];
                #pragma unroll
                for (int q = 0; q < 4; ++q)
                    u[q] = ((const uint4*)xb)[(size_t)p[q].x * 16 + glane];
                #pragma unroll
                for (int q = 0; q < 4; ++q) {
                    float w = (j + q < end) ? __int_as_float(p[q].y) : 0.f;
                    acc_edge(w, u[q], a);
                }
            }
            uint4 o;
            o.x = (uint32_t)f32_to_bf16(a[0]) | ((uint32_t)f32_to_bf16(a[1]) << 16);
            o.y = (uint32_t)f32_to_bf16(a[2]) | ((uint32_t)f32_to_bf16(a[3]) << 16);
            o.z = (uint32_t)f32_to_bf16(a[4]) | ((uint32_t)f32_to_bf16(a[5]) << 16);
            o.w = (uint32_t)f32_to_bf16(a[6]) | ((uint32_t)f32_to_bf16(a[7]) << 16);
            int cl = ((glane & 7) ^ (m & 7)) | (glane & 8);
            *reinterpret_cast<uint4*>(&As[(m * 16 + cl) * 8]) = o;
        }
    }
    __syncthreads();

    // A fragments to registers once; reused by both nh halves.
    bf16x8 af[4][4];   // [ks][mt]
    #pragma unroll
    for (int ks = 0; ks < 4; ++ks) {
        int q = ks * 4 + fq;
        int cl = ((q & 7) ^ (fr & 7)) | (q & 8);
        #pragma unroll
        for (int mt = 0; mt < 4; ++mt)
            af[ks][mt] = *(const bf16x8*)(As + (wr + mt * 16 + fr) * 128 + cl * 8);
    }

    const bf16x8* w1p = (const bf16x8*)W1F;
    const bf16x8* w2p = (const bf16x8*)W2F;

    f32x4 acc_t[4][4] = {};
    #pragma unroll
    for (int nh = 0; nh < 2; ++nh) {
        int wbase = (nh * 2 + wcid) * 16 * 64;   // 16 frags x 64 lanes per (nh,wc)
        // phase A: acc_h = A_tile @ W1[nh half]
        f32x4 acc_h[4][4] = {};
        #pragma unroll
        for (int ks = 0; ks < 4; ++ks) {
            bf16x8 wf[4];
            #pragma unroll
            for (int nt = 0; nt < 4; ++nt)
                wf[nt] = w1p[wbase + (ks * 4 + nt) * 64 + lane];
            #pragma unroll
            for (int mt = 0; mt < 4; ++mt)
                #pragma unroll
                for (int nt = 0; nt < 4; ++nt)
                    acc_h[mt][nt] = __builtin_amdgcn_mfma_f32_16x16x32_bf16(
                        af[ks][mt], wf[nt], acc_h[mt][nt], 0, 0, 0);
        }
        float bv[4];
        #pragma unroll
        for (int nt = 0; nt < 4; ++nt) bv[nt] = b1[nh * 128 + wc + nt * 16 + fr];
        __syncthreads();   // prior half's Hs consumers done
        #pragma unroll
        for (int mt = 0; mt < 4; ++mt)
            #pragma unroll
            for (int r = 0; r < 4; ++r) {
                int row = wr + mt * 16 + fq * 4 + r;
                #pragma unroll
                for (int nt = 0; nt < 4; ++nt) {
                    float v = fmaxf(acc_h[mt][nt][r] + bv[nt], 0.f);
                    Hs[row * 136 + wc + nt * 16 + fr] = f32_to_bf16(v);
                }
            }
        __syncthreads();   // Hs ready
        // phase B: acc_t += Hs @ W2[nh half rows]
        #pragma unroll
        for (int ks = 0; ks < 4; ++ks) {
            bf16x8 wf[4], hf[4];
            #pragma unroll
            for (int nt = 0; nt < 4; ++nt)
                wf[nt] = w2p[wbase + (ks * 4 + nt) * 64 + lane];
            #pragma unroll
            for (int mt = 0; mt < 4; ++mt)
                hf[mt] = *(const bf16x8*)(Hs + (wr + mt * 16 + fr) * 136 + ks * 32 + fq * 8);
            #pragma unroll
            for (int mt = 0; mt < 4; ++mt)
                #pragma unroll
                for (int nt = 0; nt < 4; ++nt)
                    acc_t[mt][nt] = __builtin_amdgcn_mfma_f32_16x16x32_bf16(
                        hf[mt], wf[nt], acc_t[mt][nt], 0, 0, 0);
        }
    }

    // epilogue: C/D layout col=lane&15, row=(lane>>4)*4+reg (m89-verified)
    #pragma unroll
    for (int mt = 0; mt < 4; ++mt)
        #pragma unroll
        for (int r = 0; r < 4; ++r) {
            int row = m0 + wr + mt * 16 + fq * 4 + r;
            if (row >= M) continue;
            #pragma unroll
            for (int nt = 0; nt < 4; ++nt)
                T[(size_t)row * 128 + wc + nt * 16 + fr] = f32_to_bf16(acc_t[mt][nt][r]);
        }
}

// ---------------------------------------------------------------------------
extern "C" void kernel_launch(void* const* d_in, const int* in_sizes, int n_in,
                              void* d_out, int out_size, void* d_ws, size_t ws_size,
                              hipStream_t stream) {
    const float* x  = (const float*)d_in[0];
    const int*   ei = (const int*)d_in[1];    // int32 (harness converts ints)
    const float* ew = (const float*)d_in[2];
    const float* W1 = (const float*)d_in[3];
    const float* b1 = (const float*)d_in[4];
    const float* W2 = (const float*)d_in[5];
    const float* b2 = (const float*)d_in[6];
    float* out = (float*)d_out;

    char* ws = (char*)d_ws;
    size_t off = 0;
    auto alloc = [&](size_t bytes) -> void* {
        void* p = ws + off;
        off = (off + bytes + 255) & ~(size_t)255;
        return p;
    };
    unsigned long long* cnt64 = (unsigned long long*)alloc((size_t)N_NODES * 8);
    float* dis   = (float*)alloc((size_t)N_NODES * 4);
    int*   rowp  = (int*)  alloc((size_t)(N_NODES + 1) * 4);
    int*   bsums = (int*)  alloc(512 * 4);
    int*   rank  = (int*)  alloc((size_t)N_EDGES * 4);
    int2*  pairs = (int2*) alloc((size_t)N_EDGES * 8);
    uint32_t* xb = (uint32_t*)alloc((size_t)N_NODES * IN_DIM * 2);
    unsigned short* W1F = (unsigned short*)alloc((size_t)IN_DIM * HID_DIM * 2);
    unsigned short* W2F = (unsigned short*)alloc((size_t)HID_DIM * OUT_DIM * 2);
    unsigned short* t   = (unsigned short*)alloc((size_t)N_NODES * OUT_DIM * 2);

    hipMemsetAsync(cnt64, 0, (size_t)N_NODES * 8, stream);

    int nn_blocks = (N_NODES + 255) / 256;   // 391
    int ne_blocks = (N_EDGES + 255) / 256;   // 3125

    // fused: histogram (atomic-unit-bound) overlapped with prep (BW-bound)
    hist_prep_kernel<<<HIST_BLOCKS + XB_BLOCKS + 256, 256, 0, stream>>>(
        ei, ew, cnt64, rank, x, xb, W1, W1F, W2, W2F);

    scan1_kernel<<<nn_blocks, 256, 0, stream>>>(cnt64, rowp, bsums, dis, N_NODES);
    scan23_kernel<<<nn_blocks, 256, 0, stream>>>(rowp, bsums, N_NODES, N_EDGES);
    place_kernel<<<ne_blocks, 256, 0, stream>>>(ei, ew, rank, rowp, dis, pairs);

    // fused aggregate+dense stack: t = relu(agg(xb) @ W1 + b1) @ W2  [bf16]
    gemm_agg_fused_kernel<<<(N_NODES + 127) / 128, 256, 0, stream>>>(
        xb, rowp, pairs, W1F, b1, W2F, t, N_NODES);

    // layer 2 aggregate: out = agg(t) + b2 [fp32]
    int agg_blocks = (N_NODES * 16) / 256;   // 6250, exact
    aggregate_kernel<false><<<agg_blocks, 256, 0, stream>>>(
        (const uint4*)t, rowp, pairs, out, b2);
}